// Round 1
// baseline (773.240 us; speedup 1.0000x reference)
//
#include <hip/hip_runtime.h>
#include <stdint.h>

// KNN behavior-cloning policy: B=1024 queries x D=512, bank N=100000, top-16 by L2,
// mean of act_bank rows [1024,32] f32.
// Strategy: bf16 MFMA GEMM for approximate scores (b2 - 2*dot), per-chunk top-k
// candidate selection, exact fp32 rerank of top-32 candidates, gather+mean.

#define NQ     1024
#define DIM    512
#define NB     100000
#define NPAD   100352          // 784 * 128
#define NTILES 784             // column tiles of 128
#define ADIM   32
#define KNB    16

typedef __attribute__((ext_vector_type(8))) short short8;
typedef __attribute__((ext_vector_type(8))) unsigned short ushort8;
typedef __attribute__((ext_vector_type(4))) float f32x4;

__device__ inline unsigned short f2bf(float f) {
  union { float f; unsigned u; } v; v.f = f;
  unsigned u = v.u;
  unsigned r = (u + 0x7fffu + ((u >> 16) & 1u)) >> 16;  // RNE
  return (unsigned short)r;
}

__device__ inline void gload16(const void* g, void* l) {
  __builtin_amdgcn_global_load_lds(
      (const __attribute__((address_space(1))) unsigned int*)g,
      (__attribute__((address_space(3))) unsigned int*)l, 16, 0, 0);
}

// ---------------- conversion + norms ----------------
__global__ __launch_bounds__(256) void convert_bank_kernel(
    const float* __restrict__ bank, unsigned short* __restrict__ bank16,
    float* __restrict__ b2) {
  const int row  = blockIdx.x * 4 + (threadIdx.x >> 6);
  const int lane = threadIdx.x & 63;
  if (row < NB) {
    const float* src = bank + (size_t)row * DIM + lane * 8;
    const float4 a = ((const float4*)src)[0];
    const float4 b = ((const float4*)src)[1];
    float ss = a.x*a.x + a.y*a.y + a.z*a.z + a.w*a.w
             + b.x*b.x + b.y*b.y + b.z*b.z + b.w*b.w;
    #pragma unroll
    for (int o = 32; o; o >>= 1) ss += __shfl_xor(ss, o);
    ushort8 o8;
    o8[0]=f2bf(a.x); o8[1]=f2bf(a.y); o8[2]=f2bf(a.z); o8[3]=f2bf(a.w);
    o8[4]=f2bf(b.x); o8[5]=f2bf(b.y); o8[6]=f2bf(b.z); o8[7]=f2bf(b.w);
    *(ushort8*)(bank16 + (size_t)row * DIM + lane * 8) = o8;
    if (lane == 0) b2[row] = ss;
  } else {
    ushort8 z = {0,0,0,0,0,0,0,0};
    *(ushort8*)(bank16 + (size_t)row * DIM + lane * 8) = z;
    if (lane == 0) b2[row] = 1e30f;   // pad rows never selected
  }
}

__global__ __launch_bounds__(256) void convert_obs_kernel(
    const float* __restrict__ obs, unsigned short* __restrict__ o16) {
  const int row  = blockIdx.x * 4 + (threadIdx.x >> 6);
  const int lane = threadIdx.x & 63;
  const float* src = obs + (size_t)row * DIM + lane * 8;
  const float4 a = ((const float4*)src)[0];
  const float4 b = ((const float4*)src)[1];
  ushort8 o8;
  o8[0]=f2bf(a.x); o8[1]=f2bf(a.y); o8[2]=f2bf(a.z); o8[3]=f2bf(a.w);
  o8[4]=f2bf(b.x); o8[5]=f2bf(b.y); o8[6]=f2bf(b.z); o8[7]=f2bf(b.w);
  *(ushort8*)(o16 + (size_t)row * DIM + lane * 8) = o8;
}

// ---------------- bf16 MFMA GEMM (m97 structure: 128x128 tile, BK=64) ----------------
// scores[m][col_in_chunk] = b2[n] - 2 * dot(obs[m], bank[n])
__global__ __launch_bounds__(256) void gemm_kernel(
    const unsigned short* __restrict__ A16,   // obs bf16 [1024][512]
    const unsigned short* __restrict__ B16,   // bank bf16 [NPAD][512]
    const float* __restrict__ b2,
    float* __restrict__ scores, int col_base, int nc_stride) {
  __shared__ unsigned short As[128 * 64];
  __shared__ unsigned short Bs[128 * 64];
  const int tid  = threadIdx.x;
  const int lane = tid & 63;
  const int w    = tid >> 6;
  const int tile_m = blockIdx.x * 128;
  const int col0   = blockIdx.y * 128;        // within chunk
  const int gcol0  = col_base + col0;         // global bank row base
  const int wm = (w >> 1) * 64;
  const int wn = (w & 1) * 64;

  f32x4 acc[4][4];
  #pragma unroll
  for (int i = 0; i < 4; ++i)
    #pragma unroll
    for (int j = 0; j < 4; ++j)
      acc[i][j] = (f32x4){0.f, 0.f, 0.f, 0.f};

  const int srow = lane >> 3;        // 0..7 row within 8-row stage block
  const int skel = (lane & 7) * 8;   // k element offset 0..56

  for (int kt = 0; kt < 8; ++kt) {
    const int k0 = kt * 64;
    #pragma unroll
    for (int j = 0; j < 4; ++j) {
      const int rb = (w * 4 + j) * 8;
      const unsigned short* ga = A16 + (size_t)(tile_m + rb + srow) * DIM + k0 + skel;
      const unsigned short* gb = B16 + (size_t)(gcol0 + rb + srow) * DIM + k0 + skel;
      gload16(ga, (char*)As + (w * 4 + j) * 1024);
      gload16(gb, (char*)Bs + (w * 4 + j) * 1024);
    }
    __syncthreads();

    short8 af[4][2], bf[4][2];
    #pragma unroll
    for (int mi = 0; mi < 4; ++mi)
      #pragma unroll
      for (int kk = 0; kk < 2; ++kk)
        af[mi][kk] = *(const short8*)&As[(wm + mi*16 + (lane & 15)) * 64 + kk*32 + (lane >> 4) * 8];
    #pragma unroll
    for (int nj = 0; nj < 4; ++nj)
      #pragma unroll
      for (int kk = 0; kk < 2; ++kk)
        bf[nj][kk] = *(const short8*)&Bs[(wn + nj*16 + (lane & 15)) * 64 + kk*32 + (lane >> 4) * 8];

    #pragma unroll
    for (int mi = 0; mi < 4; ++mi)
      #pragma unroll
      for (int nj = 0; nj < 4; ++nj) {
        acc[mi][nj] = __builtin_amdgcn_mfma_f32_16x16x32_bf16(af[mi][0], bf[nj][0], acc[mi][nj], 0, 0, 0);
        acc[mi][nj] = __builtin_amdgcn_mfma_f32_16x16x32_bf16(af[mi][1], bf[nj][1], acc[mi][nj], 0, 0, 0);
      }
    __syncthreads();
  }

  // epilogue: C/D layout col=lane&15 (n), row=(lane>>4)*4+r (m)
  #pragma unroll
  for (int mi = 0; mi < 4; ++mi) {
    const int mbase = tile_m + wm + mi * 16 + ((lane >> 4) << 2);
    #pragma unroll
    for (int nj = 0; nj < 4; ++nj) {
      const int nl  = wn + nj * 16 + (lane & 15);
      const int ncl = col0 + nl;
      const float b2v = b2[gcol0 + nl];
      #pragma unroll
      for (int r = 0; r < 4; ++r)
        scores[(size_t)(mbase + r) * nc_stride + ncl] = b2v - 2.0f * acc[mi][nj][r];
    }
  }
}

// ---------------- per-chunk candidate selection ----------------
// block = 256 (4 waves), one block per query. Each wave scans chunk_cols/4
// columns; per-thread sorted top-8 in registers; wave head-merge extracts WK
// smallest -> cand[q][chunk][wave*WK + k].
__global__ __launch_bounds__(256) void select_kernel(
    const float* __restrict__ scores, float* __restrict__ cand_s,
    int* __restrict__ cand_i, int nc_stride, int chunk_cols, int col_base,
    int c, int nch, int WK) {
  const int q    = blockIdx.x;
  const int lane = threadIdx.x & 63;
  const int w    = threadIdx.x >> 6;
  const int span = chunk_cols >> 2;
  const int sb   = w * span;
  const int se   = sb + span;
  const float* rowp = scores + (size_t)q * nc_stride;

  float ts[8]; int ti[8];
  #pragma unroll
  for (int i = 0; i < 8; ++i) { ts[i] = 1e38f; ti[i] = -1; }

  auto ins = [&](float s, int j) {
    if (s < ts[7]) {
      float cs = s; int ci = col_base + j;
      #pragma unroll
      for (int p = 0; p < 8; ++p) {
        if (cs < ts[p]) {
          float tf = ts[p]; ts[p] = cs; cs = tf;
          int   tt = ti[p]; ti[p] = ci; ci = tt;
        }
      }
    }
  };

  int t = sb;
  for (; t + 256 <= se; t += 256) {
    const int j = t + lane * 4;
    const float4 v = *(const float4*)(rowp + j);
    ins(v.x, j); ins(v.y, j + 1); ins(v.z, j + 2); ins(v.w, j + 3);
  }
  for (int j = t + lane; j < se; j += 64) ins(rowp[j], j);

  // wave head-merge: extract WK smallest across 64 sorted lists
  const size_t base = ((size_t)q * nch + c) * (size_t)(4 * WK) + (size_t)w * WK;
  for (int k = 0; k < WK; ++k) {
    float bv = ts[0]; int bi = ti[0]; int bl = lane;
    #pragma unroll
    for (int o = 32; o; o >>= 1) {
      float ov = __shfl_xor(bv, o); int oi = __shfl_xor(bi, o); int ol = __shfl_xor(bl, o);
      if (ov < bv || (ov == bv && ol < bl)) { bv = ov; bi = oi; bl = ol; }
    }
    if (lane == bl) {  // winner shifts its sorted list down (static indices only)
      #pragma unroll
      for (int p = 0; p < 7; ++p) { ts[p] = ts[p+1]; ti[p] = ti[p+1]; }
      ts[7] = 1e38f; ti[7] = -1;
    }
    if (lane == 0) { cand_s[base + k] = bv; cand_i[base + k] = bi; }
  }
}

// ---------------- exact rerank + gather/mean ----------------
__global__ __launch_bounds__(256) void rerank_kernel(
    const float* __restrict__ cand_s, const int* __restrict__ cand_i,
    const float* __restrict__ obs, const float* __restrict__ bank,
    const float* __restrict__ acts, float* __restrict__ out, int ncand) {
  __shared__ float lss[2048];
  __shared__ int   lii[2048];
  __shared__ int   selidx[32];
  __shared__ float exd[32];
  __shared__ int   sel2[16];
  const int q    = blockIdx.x;
  const int tid  = threadIdx.x;
  const int lane = tid & 63;
  const int w    = tid >> 6;

  for (int i = tid; i < ncand; i += 256) {
    lss[i] = cand_s[(size_t)q * ncand + i];
    lii[i] = cand_i[(size_t)q * ncand + i];
  }
  __syncthreads();

  // approx top-32 via threshold extraction (read-only LDS, no invalidation races)
  if (w == 0) {
    float lastv = -1e38f; int lastp = -1;
    for (int k = 0; k < 32; ++k) {
      float bv = 1e38f; int bi = -1; int bp = ncand;
      for (int i = lane; i < ncand; i += 64) {
        const float v = lss[i];
        const bool gt = (v > lastv) || (v == lastv && i > lastp);
        const bool lt = (v < bv) || (v == bv && i < bp);
        if (gt && lt) { bv = v; bi = lii[i]; bp = i; }
      }
      #pragma unroll
      for (int o = 32; o; o >>= 1) {
        float ov = __shfl_xor(bv, o); int oi = __shfl_xor(bi, o); int op = __shfl_xor(bp, o);
        if (ov < bv || (ov == bv && op < bp)) { bv = ov; bi = oi; bp = op; }
      }
      if (lane == 0) selidx[k] = bi;
      lastv = bv; lastp = bp;
    }
  }
  __syncthreads();

  // exact fp32 distances for the 32 candidates (one wave per candidate, round-robin)
  const float* qp = obs + (size_t)q * DIM + lane * 8;
  const float4 qa = ((const float4*)qp)[0];
  const float4 qb = ((const float4*)qp)[1];
  for (int c2 = w; c2 < 32; c2 += 4) {
    const int idx = selidx[c2];
    const float* bp_ = bank + (size_t)idx * DIM + lane * 8;
    const float4 ba = ((const float4*)bp_)[0];
    const float4 bb = ((const float4*)bp_)[1];
    const float d0 = qa.x-ba.x, d1 = qa.y-ba.y, d2 = qa.z-ba.z, d3 = qa.w-ba.w;
    const float d4 = qb.x-bb.x, d5 = qb.y-bb.y, d6 = qb.z-bb.z, d7 = qb.w-bb.w;
    float ss = d0*d0 + d1*d1 + d2*d2 + d3*d3 + d4*d4 + d5*d5 + d6*d6 + d7*d7;
    #pragma unroll
    for (int o = 32; o; o >>= 1) ss += __shfl_xor(ss, o);
    if (lane == 0) exd[c2] = ss;
  }
  __syncthreads();

  // exact top-16 of 32
  if (w == 0) {
    const float v  = (lane < 32) ? exd[lane] : 1e38f;
    const int   id = (lane < 32) ? selidx[lane] : -1;
    float lastv = -1e38f; int lastp = -1;
    for (int k = 0; k < 16; ++k) {
      float bv = 1e38f; int bi = -1; int bp = 64;
      const bool gt = (v > lastv) || (v == lastv && lane > lastp);
      if (gt) { bv = v; bi = id; bp = lane; }
      #pragma unroll
      for (int o = 32; o; o >>= 1) {
        float ov = __shfl_xor(bv, o); int oi = __shfl_xor(bi, o); int op = __shfl_xor(bp, o);
        if (ov < bv || (ov == bv && op < bp)) { bv = ov; bi = oi; bp = op; }
      }
      if (lane == 0) sel2[k] = bi;
      lastv = bv; lastp = bp;
    }
  }
  __syncthreads();

  if (tid < ADIM) {
    float s = 0.f;
    #pragma unroll
    for (int t2 = 0; t2 < KNB; ++t2) s += acts[(size_t)sel2[t2] * ADIM + tid];
    out[(size_t)q * ADIM + tid] = s * (1.0f / KNB);
  }
}

// ---------------- host launch ----------------
extern "C" void kernel_launch(void* const* d_in, const int* in_sizes, int n_in,
                              void* d_out, int out_size, void* d_ws, size_t ws_size,
                              hipStream_t stream) {
  const float* obs  = (const float*)d_in[0];
  const float* bank = (const float*)d_in[1];
  const float* acts = (const float*)d_in[2];
  float* out = (float*)d_out;
  char* ws = (char*)d_ws;

  size_t off = 0;
  auto take = [&](size_t b) { size_t o = off; off += (b + 255) & ~(size_t)255; return o; };
  const size_t off_b16 = take((size_t)NPAD * DIM * 2);
  const size_t off_o16 = take((size_t)NQ * DIM * 2);
  const size_t off_b2  = take((size_t)NPAD * 4);
  const size_t fixed   = off;

  // choose chunking to fit ws: {nch, WK}
  const int cfg_nch[4] = {8, 16, 16, 32};
  const int cfg_wk[4]  = {32, 32, 16, 16};
  int nch = 32, WK = 16, tpc = 0, NC = 0;
  size_t off_scores = 0, off_cs = 0, off_ci = 0;
  for (int i = 0; i < 4; ++i) {
    const int n  = cfg_nch[i];
    const int tp = (NTILES + n - 1) / n;
    const int ncc = tp * 128;
    const size_t sc_b = (size_t)NQ * ncc * 4;
    const size_t cd_b = (size_t)NQ * (size_t)n * 4 * cfg_wk[i] * 4;
    const size_t tot = fixed + ((sc_b + 255) & ~(size_t)255) + 2 * ((cd_b + 255) & ~(size_t)255);
    if (tot <= ws_size || i == 3) {
      nch = n; WK = cfg_wk[i]; tpc = tp; NC = ncc;
      off = fixed;
      off_scores = take(sc_b);
      off_cs = take(cd_b);
      off_ci = take(cd_b);
      break;
    }
  }

  unsigned short* bank16 = (unsigned short*)(ws + off_b16);
  unsigned short* obs16  = (unsigned short*)(ws + off_o16);
  float* b2     = (float*)(ws + off_b2);
  float* scores = (float*)(ws + off_scores);
  float* cand_s = (float*)(ws + off_cs);
  int*   cand_i = (int*)(ws + off_ci);

  convert_bank_kernel<<<NPAD / 4, 256, 0, stream>>>(bank, bank16, b2);
  convert_obs_kernel<<<NQ / 4, 256, 0, stream>>>(obs, obs16);

  for (int c = 0; c < nch; ++c) {
    const int tile0 = c * tpc;
    int tiles = NTILES - tile0;
    if (tiles > tpc) tiles = tpc;
    if (tiles <= 0) break;
    const int col_base = tile0 * 128;
    const int cols = tiles * 128;
    gemm_kernel<<<dim3(8, tiles), 256, 0, stream>>>(obs16, bank16, b2, scores, col_base, NC);
    select_kernel<<<NQ, 256, 0, stream>>>(scores, cand_s, cand_i, NC, cols, col_base, c, nch, WK);
  }
  rerank_kernel<<<NQ, 256, 0, stream>>>(cand_s, cand_i, obs, bank, acts, out, nch * 4 * WK);
}

// Round 2
// 554.162 us; speedup vs baseline: 1.3953x; 1.3953x over previous
//
#include <hip/hip_runtime.h>
#include <stdint.h>

// KNN BC policy: B=1024 x D=512 queries vs N=100000 bank, top-16 L2, mean of acts [1024,32].
// R2: fp16 MFMA GEMM with top-8-per-row-per-tile selection FUSED into the epilogue
// (kills the 822 MB score round-trip), then per-query candidate merge + exact fp32
// rerank of top-32 -> top-16 -> mean.

#define NQ     1024
#define DIM    512
#define NB     100000
#define NPAD   100352          // 784 * 128
#define NTILES 784
#define ADIM   32
#define KNB    16
#define SC_LD  132             // score LDS row stride (floats): 128 + 4 pad
#define NCAND  (NTILES * 8)    // 6272 candidates per query
#define QUARTER (NCAND / 4)    // 1568 per wave

typedef __attribute__((ext_vector_type(8))) _Float16 half8;
typedef __attribute__((ext_vector_type(4))) float f32x4;

__device__ inline int   f2i(float f) { union { float f; int i; } u; u.f = f; return u.i; }
__device__ inline float i2f(int i)   { union { int i; float f; } u; u.i = i; return u.f; }

__device__ inline void gload16(const void* g, void* l) {
  __builtin_amdgcn_global_load_lds(
      (const __attribute__((address_space(1))) unsigned int*)g,
      (__attribute__((address_space(3))) unsigned int*)l, 16, 0, 0);
}

// ---------------- conversion + norms ----------------
__global__ __launch_bounds__(256) void convert_bank_kernel(
    const float* __restrict__ bank, _Float16* __restrict__ bank16,
    float* __restrict__ b2) {
  const int row  = blockIdx.x * 4 + (threadIdx.x >> 6);
  const int lane = threadIdx.x & 63;
  if (row < NB) {
    const float* src = bank + (size_t)row * DIM + lane * 8;
    const float4 a = ((const float4*)src)[0];
    const float4 b = ((const float4*)src)[1];
    float ss = a.x*a.x + a.y*a.y + a.z*a.z + a.w*a.w
             + b.x*b.x + b.y*b.y + b.z*b.z + b.w*b.w;
    #pragma unroll
    for (int o = 32; o; o >>= 1) ss += __shfl_xor(ss, o);
    half8 o8;
    o8[0]=(_Float16)a.x; o8[1]=(_Float16)a.y; o8[2]=(_Float16)a.z; o8[3]=(_Float16)a.w;
    o8[4]=(_Float16)b.x; o8[5]=(_Float16)b.y; o8[6]=(_Float16)b.z; o8[7]=(_Float16)b.w;
    *(half8*)(bank16 + (size_t)row * DIM + lane * 8) = o8;
    if (lane == 0) b2[row] = ss;
  } else {
    half8 z = {0,0,0,0,0,0,0,0};
    *(half8*)(bank16 + (size_t)row * DIM + lane * 8) = z;
    if (lane == 0) b2[row] = 1e30f;   // pad rows never selected
  }
}

__global__ __launch_bounds__(256) void convert_obs_kernel(
    const float* __restrict__ obs, _Float16* __restrict__ o16) {
  const int row  = blockIdx.x * 4 + (threadIdx.x >> 6);
  const int lane = threadIdx.x & 63;
  const float* src = obs + (size_t)row * DIM + lane * 8;
  const float4 a = ((const float4*)src)[0];
  const float4 b = ((const float4*)src)[1];
  half8 o8;
  o8[0]=(_Float16)a.x; o8[1]=(_Float16)a.y; o8[2]=(_Float16)a.z; o8[3]=(_Float16)a.w;
  o8[4]=(_Float16)b.x; o8[5]=(_Float16)b.y; o8[6]=(_Float16)b.z; o8[7]=(_Float16)b.w;
  *(half8*)(o16 + (size_t)row * DIM + lane * 8) = o8;
}

// ---------------- fp16 MFMA GEMM + fused per-tile top-8 selection ----------------
// block = 128(M) x 128(N) tile; scores = b2[n] - 2*dot; emits top-8 (score, idx)
// per query row per 128-col tile into cand[q][tile][8].
__global__ __launch_bounds__(256) void gemm_select_kernel(
    const _Float16* __restrict__ A16,   // obs fp16 [1024][512]
    const _Float16* __restrict__ B16,   // bank fp16 [NPAD][512]
    const float* __restrict__ b2,
    float2* __restrict__ cand) {
  __shared__ char smem[64 * SC_LD * 4];          // 33792 B; staging overlays scores
  _Float16* As = (_Float16*)smem;                // 128x64 fp16 = 16 KB
  _Float16* Bs = (_Float16*)(smem + 16384);      // 128x64 fp16 = 16 KB
  float*    sc = (float*)smem;                   // 64 x SC_LD f32 (per phase)

  const int tid  = threadIdx.x;
  const int lane = tid & 63;
  const int w    = tid >> 6;
  const int tile   = blockIdx.y;
  const int tile_m = blockIdx.x * 128;
  const int gcol0  = tile * 128;
  const int wm = (w >> 1) * 64;
  const int wn = (w & 1) * 64;

  f32x4 acc[4][4];
  #pragma unroll
  for (int i = 0; i < 4; ++i)
    #pragma unroll
    for (int j = 0; j < 4; ++j)
      acc[i][j] = (f32x4){0.f, 0.f, 0.f, 0.f};

  const int srow = lane >> 3;        // 0..7 row within 8-row stage block
  const int skel = (lane & 7) * 8;   // k element offset 0..56

  for (int kt = 0; kt < 8; ++kt) {
    const int k0 = kt * 64;
    #pragma unroll
    for (int j = 0; j < 4; ++j) {
      const int rb = (w * 4 + j) * 8;
      gload16(A16 + (size_t)(tile_m + rb + srow) * DIM + k0 + skel,
              (char*)As + (w * 4 + j) * 1024);
      gload16(B16 + (size_t)(gcol0 + rb + srow) * DIM + k0 + skel,
              (char*)Bs + (w * 4 + j) * 1024);
    }
    __syncthreads();

    half8 af[4][2], bf[4][2];
    #pragma unroll
    for (int mi = 0; mi < 4; ++mi)
      #pragma unroll
      for (int kk = 0; kk < 2; ++kk)
        af[mi][kk] = *(const half8*)&As[(wm + mi*16 + (lane & 15)) * 64 + kk*32 + (lane >> 4) * 8];
    #pragma unroll
    for (int nj = 0; nj < 4; ++nj)
      #pragma unroll
      for (int kk = 0; kk < 2; ++kk)
        bf[nj][kk] = *(const half8*)&Bs[(wn + nj*16 + (lane & 15)) * 64 + kk*32 + (lane >> 4) * 8];

    #pragma unroll
    for (int mi = 0; mi < 4; ++mi)
      #pragma unroll
      for (int nj = 0; nj < 4; ++nj) {
        acc[mi][nj] = __builtin_amdgcn_mfma_f32_16x16x32_f16(af[mi][0], bf[nj][0], acc[mi][nj], 0, 0, 0);
        acc[mi][nj] = __builtin_amdgcn_mfma_f32_16x16x32_f16(af[mi][1], bf[nj][1], acc[mi][nj], 0, 0, 0);
      }
    __syncthreads();
  }

  // ---- fused epilogue: 2 phases of 64 rows; scores -> LDS -> per-row top-8 ----
  // C/D layout: col = lane&15 (+nj*16+wn), row = (lane>>4)*4 + r (+mi*16+wm).
  #pragma unroll
  for (int p = 0; p < 2; ++p) {
    if ((w >> 1) == p) {
      #pragma unroll
      for (int nj = 0; nj < 4; ++nj) {
        const int colt = wn + nj * 16 + (lane & 15);
        const float b2v = b2[gcol0 + colt];
        #pragma unroll
        for (int mi = 0; mi < 4; ++mi) {
          const int r0 = mi * 16 + ((lane >> 4) << 2);
          #pragma unroll
          for (int r = 0; r < 4; ++r)
            sc[(r0 + r) * SC_LD + colt] = b2v - 2.0f * acc[mi][nj][r];
        }
      }
    }
    __syncthreads();

    // selection: 4 threads per row, each scans a 32-col window (rotated for banks)
    const int rrow = tid >> 2;          // 0..63
    const int part = tid & 3;
    const int c0 = ((rrow + part) & 3) * 32;
    float ts[8]; int ti[8];
    #pragma unroll
    for (int i = 0; i < 8; ++i) { ts[i] = 1e38f; ti[i] = -1; }

    auto ins = [&](float s, int gidx) {
      if (s < ts[7]) {
        float cs = s; int ci = gidx;
        #pragma unroll
        for (int pp = 0; pp < 8; ++pp) {
          if (cs < ts[pp]) {
            float tf = ts[pp]; ts[pp] = cs; cs = tf;
            int   tt = ti[pp]; ti[pp] = ci; ci = tt;
          }
        }
      }
    };

    const float* rowp = sc + rrow * SC_LD;
    #pragma unroll
    for (int cc2 = 0; cc2 < 32; cc2 += 4) {
      const int cc = (cc2 + part * 8) & 31;     // stagger banks across parts
      const int j = c0 + cc;
      const float4 v = *(const float4*)(rowp + j);
      ins(v.x, gcol0 + j); ins(v.y, gcol0 + j + 1);
      ins(v.z, gcol0 + j + 2); ins(v.w, gcol0 + j + 3);
    }

    // 4-lane head-merge: extract row top-8
    float2* outp = cand + ((size_t)(tile_m + p * 64 + rrow) * NTILES + tile) * 8;
    for (int k = 0; k < 8; ++k) {
      float bv = ts[0]; int bi = ti[0]; int bp = part;
      { float ov = __shfl_xor(bv, 1); int oi = __shfl_xor(bi, 1); int op = __shfl_xor(bp, 1);
        if (ov < bv || (ov == bv && op < bp)) { bv = ov; bi = oi; bp = op; } }
      { float ov = __shfl_xor(bv, 2); int oi = __shfl_xor(bi, 2); int op = __shfl_xor(bp, 2);
        if (ov < bv || (ov == bv && op < bp)) { bv = ov; bi = oi; bp = op; } }
      if (part == bp) {   // winner pops its sorted list
        #pragma unroll
        for (int pp = 0; pp < 7; ++pp) { ts[pp] = ts[pp+1]; ti[pp] = ti[pp+1]; }
        ts[7] = 1e38f; ti[7] = -1;
      }
      if (part == 0) outp[k] = make_float2(bv, i2f(bi));
    }
    __syncthreads();
  }
}

// ---------------- per-query candidate merge + exact rerank ----------------
__global__ __launch_bounds__(256) void topk_kernel(
    const float2* __restrict__ cand, const float* __restrict__ obs,
    const float* __restrict__ bank, const float* __restrict__ acts,
    float* __restrict__ out) {
  __shared__ float2 lc[NCAND];       // 50176 B
  __shared__ float2 wtop[128];
  __shared__ int   selidx[32];
  __shared__ float exd[32];
  __shared__ int   sel2[16];
  const int q    = blockIdx.x;
  const int tid  = threadIdx.x;
  const int lane = tid & 63;
  const int w    = tid >> 6;

  for (int i = tid; i < NCAND; i += 256) lc[i] = cand[(size_t)q * NCAND + i];
  __syncthreads();

  // per-wave quarter: per-lane sorted top-10, then 32 head-extractions
  float ts[10]; int ti[10];
  #pragma unroll
  for (int i = 0; i < 10; ++i) { ts[i] = 1e38f; ti[i] = -1; }
  for (int i = w * QUARTER + lane; i < (w + 1) * QUARTER; i += 64) {
    const float2 e = lc[i];
    const float s = e.x;
    if (s < ts[9]) {
      float cs = s; int ci = f2i(e.y);
      #pragma unroll
      for (int pp = 0; pp < 10; ++pp) {
        if (cs < ts[pp]) {
          float tf = ts[pp]; ts[pp] = cs; cs = tf;
          int   tt = ti[pp]; ti[pp] = ci; ci = tt;
        }
      }
    }
  }
  for (int k = 0; k < 32; ++k) {
    float bv = ts[0]; int bi = ti[0]; int bl = lane;
    #pragma unroll
    for (int o = 32; o; o >>= 1) {
      float ov = __shfl_xor(bv, o); int oi = __shfl_xor(bi, o); int ol = __shfl_xor(bl, o);
      if (ov < bv || (ov == bv && ol < bl)) { bv = ov; bi = oi; bl = ol; }
    }
    if (lane == bl) {
      #pragma unroll
      for (int pp = 0; pp < 9; ++pp) { ts[pp] = ts[pp+1]; ti[pp] = ti[pp+1]; }
      ts[9] = 1e38f; ti[9] = -1;
    }
    if (lane == 0) wtop[w * 32 + k] = make_float2(bv, i2f(bi));
  }
  __syncthreads();

  // wave 0: exact top-32 of the 128 wave winners
  if (w == 0) {
    float2 e0 = wtop[lane], e1 = wtop[64 + lane];
    float s0 = e0.x, s1 = e1.x;
    int   i0 = f2i(e0.y), i1 = f2i(e1.y);
    if (s1 < s0) { float tf = s0; s0 = s1; s1 = tf; int tt = i0; i0 = i1; i1 = tt; }
    for (int k = 0; k < 32; ++k) {
      float bv = s0; int bi = i0; int bl = lane;
      #pragma unroll
      for (int o = 32; o; o >>= 1) {
        float ov = __shfl_xor(bv, o); int oi = __shfl_xor(bi, o); int ol = __shfl_xor(bl, o);
        if (ov < bv || (ov == bv && ol < bl)) { bv = ov; bi = oi; bl = ol; }
      }
      if (lane == bl) { s0 = s1; i0 = i1; s1 = 1e38f; i1 = -1; }
      if (lane == 0) selidx[k] = bi;
    }
  }
  __syncthreads();

  // exact fp32 distances for the 32 candidates (one wave per candidate, round-robin)
  const float* qp = obs + (size_t)q * DIM + lane * 8;
  const float4 qa = ((const float4*)qp)[0];
  const float4 qb = ((const float4*)qp)[1];
  for (int c2 = w; c2 < 32; c2 += 4) {
    const int idx = selidx[c2];
    const float* bp_ = bank + (size_t)idx * DIM + lane * 8;
    const float4 ba = ((const float4*)bp_)[0];
    const float4 bb = ((const float4*)bp_)[1];
    const float d0 = qa.x-ba.x, d1 = qa.y-ba.y, d2 = qa.z-ba.z, d3 = qa.w-ba.w;
    const float d4 = qb.x-bb.x, d5 = qb.y-bb.y, d6 = qb.z-bb.z, d7 = qb.w-bb.w;
    float ss = d0*d0 + d1*d1 + d2*d2 + d3*d3 + d4*d4 + d5*d5 + d6*d6 + d7*d7;
    #pragma unroll
    for (int o = 32; o; o >>= 1) ss += __shfl_xor(ss, o);
    if (lane == 0) exd[c2] = ss;
  }
  __syncthreads();

  // exact top-16 of 32
  if (w == 0) {
    const float v  = (lane < 32) ? exd[lane] : 1e38f;
    const int   id = (lane < 32) ? selidx[lane] : -1;
    float lastv = -1e38f; int lastp = -1;
    for (int k = 0; k < 16; ++k) {
      float bv = 1e38f; int bi = -1; int bp = 64;
      const bool gt = (v > lastv) || (v == lastv && lane > lastp);
      if (gt) { bv = v; bi = id; bp = lane; }
      #pragma unroll
      for (int o = 32; o; o >>= 1) {
        float ov = __shfl_xor(bv, o); int oi = __shfl_xor(bi, o); int op = __shfl_xor(bp, o);
        if (ov < bv || (ov == bv && op < bp)) { bv = ov; bi = oi; bp = op; }
      }
      if (lane == 0) sel2[k] = bi;
      lastv = bv; lastp = bp;
    }
  }
  __syncthreads();

  if (tid < ADIM) {
    float s = 0.f;
    #pragma unroll
    for (int t2 = 0; t2 < KNB; ++t2) s += acts[(size_t)sel2[t2] * ADIM + tid];
    out[(size_t)q * ADIM + tid] = s * (1.0f / KNB);
  }
}

// ---------------- host launch ----------------
extern "C" void kernel_launch(void* const* d_in, const int* in_sizes, int n_in,
                              void* d_out, int out_size, void* d_ws, size_t ws_size,
                              hipStream_t stream) {
  const float* obs  = (const float*)d_in[0];
  const float* bank = (const float*)d_in[1];
  const float* acts = (const float*)d_in[2];
  float* out = (float*)d_out;
  char* ws = (char*)d_ws;

  size_t off = 0;
  auto take = [&](size_t b) { size_t o = off; off += (b + 255) & ~(size_t)255; return o; };
  const size_t off_b16  = take((size_t)NPAD * DIM * 2);          // 102.8 MB
  const size_t off_o16  = take((size_t)NQ * DIM * 2);            // 1 MB
  const size_t off_b2   = take((size_t)NPAD * 4);                // 0.4 MB
  const size_t off_cand = take((size_t)NQ * NTILES * 8 * 8);     // 51.4 MB

  _Float16* bank16 = (_Float16*)(ws + off_b16);
  _Float16* obs16  = (_Float16*)(ws + off_o16);
  float*  b2   = (float*)(ws + off_b2);
  float2* cand = (float2*)(ws + off_cand);

  convert_bank_kernel<<<NPAD / 4, 256, 0, stream>>>(bank, bank16, b2);
  convert_obs_kernel<<<NQ / 4, 256, 0, stream>>>(obs, obs16);
  gemm_select_kernel<<<dim3(8, NTILES), 256, 0, stream>>>(obs16, bank16, b2, cand);
  topk_kernel<<<NQ, 256, 0, stream>>>(cand, obs, bank, acts, out);
}

// Round 3
// 537.674 us; speedup vs baseline: 1.4381x; 1.0307x over previous
//
#include <hip/hip_runtime.h>
#include <stdint.h>

// KNN BC policy: B=1024 x D=512 queries vs N=100000 bank, top-16 L2, mean of acts [1024,32].
// R3: swapped-operand 32x32x16 fp16 MFMA (D[n][q], q = lane-local) -> selection is pure
// in-register per-thread top-8; T2 XOR-swizzled LDS (both-sides with global_load_lds);
// top-8 per 256-row block -> 3136 cand/query -> merge + exact fp32 rerank top-32 -> top-16.

#define NQ     1024
#define DIM    512
#define NB     100000
#define NPAD   100352          // 392 * 256
#define NBLK   392             // n-blocks of 256 rows
#define ADIM   32
#define KNB    16
#define NCAND  (NBLK * 8)      // 3136 candidates per query
#define QUARTER (NCAND / 4)    // 784 per wave in topk

typedef __attribute__((ext_vector_type(8)))  _Float16 half8;
typedef __attribute__((ext_vector_type(16))) float f32x16;

__device__ inline int   f2i(float f) { union { float f; int i; } u; u.f = f; return u.i; }
__device__ inline float i2f(int i)   { union { int i; float f; } u; u.i = i; return u.f; }

__device__ inline void gload16(const void* g, void* l) {
  __builtin_amdgcn_global_load_lds(
      (const __attribute__((address_space(1))) unsigned int*)g,
      (__attribute__((address_space(3))) unsigned int*)l, 16, 0, 0);
}

// ---------------- conversion + norms ----------------
__global__ __launch_bounds__(256) void convert_bank_kernel(
    const float* __restrict__ bank, _Float16* __restrict__ bank16,
    float* __restrict__ b2) {
  const int row  = blockIdx.x * 4 + (threadIdx.x >> 6);
  const int lane = threadIdx.x & 63;
  if (row < NB) {
    const float* src = bank + (size_t)row * DIM + lane * 8;
    const float4 a = ((const float4*)src)[0];
    const float4 b = ((const float4*)src)[1];
    float ss = a.x*a.x + a.y*a.y + a.z*a.z + a.w*a.w
             + b.x*b.x + b.y*b.y + b.z*b.z + b.w*b.w;
    #pragma unroll
    for (int o = 32; o; o >>= 1) ss += __shfl_xor(ss, o);
    half8 o8;
    o8[0]=(_Float16)a.x; o8[1]=(_Float16)a.y; o8[2]=(_Float16)a.z; o8[3]=(_Float16)a.w;
    o8[4]=(_Float16)b.x; o8[5]=(_Float16)b.y; o8[6]=(_Float16)b.z; o8[7]=(_Float16)b.w;
    *(half8*)(bank16 + (size_t)row * DIM + lane * 8) = o8;
    if (lane == 0) b2[row] = ss;
  } else {
    half8 z = {0,0,0,0,0,0,0,0};
    *(half8*)(bank16 + (size_t)row * DIM + lane * 8) = z;
    if (lane == 0) b2[row] = 1e30f;   // pad rows never selected
  }
}

__global__ __launch_bounds__(256) void convert_obs_kernel(
    const float* __restrict__ obs, _Float16* __restrict__ o16) {
  const int row  = blockIdx.x * 4 + (threadIdx.x >> 6);
  const int lane = threadIdx.x & 63;
  const float* src = obs + (size_t)row * DIM + lane * 8;
  const float4 a = ((const float4*)src)[0];
  const float4 b = ((const float4*)src)[1];
  half8 o8;
  o8[0]=(_Float16)a.x; o8[1]=(_Float16)a.y; o8[2]=(_Float16)a.z; o8[3]=(_Float16)a.w;
  o8[4]=(_Float16)b.x; o8[5]=(_Float16)b.y; o8[6]=(_Float16)b.z; o8[7]=(_Float16)b.w;
  *(half8*)(o16 + (size_t)row * DIM + lane * 8) = o8;
}

// ---------------- swapped-operand GEMM + in-register top-8 ----------------
// Block: 256 n-rows x 128 queries. 8 waves = 2 (n-half) x 4 (q-group of 32).
// acc[s] = mfma_32x32x16(bank_frag, obs_frag): D col = lane&31 = query,
// row = (reg&3)+8*(reg>>2)+4*(lane>>5) = n within 32-subtile.
// score s = 0.5*b2[n] - dot  (monotone in d2); keep per-lane smallest-8.
__global__ __launch_bounds__(512) void gemm_select_kernel(
    const _Float16* __restrict__ A16,   // bank fp16 [NPAD][512]
    const _Float16* __restrict__ B16,   // obs  fp16 [1024][512]
    const float* __restrict__ b2,
    float2* __restrict__ cand) {
  __shared__ char smem[32768 + 16384 + 1024];
  _Float16* As = (_Float16*)smem;                     // [256][64] swizzled
  _Float16* Bs = (_Float16*)(smem + 32768);           // [128][64] swizzled
  float*    b2s = (float*)(smem + 32768 + 16384);     // [256]
  float2*   mbuf = (float2*)smem;                     // epilogue reuse (16 KB)

  const int tid = threadIdx.x;
  const int l   = tid & 63;
  const int w   = tid >> 6;
  const int wq  = w & 3;       // query group (32 queries)
  const int wnh = w >> 2;      // n half (128 rows)
  const int nblk = blockIdx.x;
  const int qblk = blockIdx.y;
  const int n0  = nblk * 256;
  const int q0g = qblk * 128;

  if (tid < 256) b2s[tid] = b2[n0 + tid];

  f32x16 acc[4];
  #pragma unroll
  for (int s = 0; s < 4; ++s)
    #pragma unroll
    for (int r = 0; r < 16; ++r) acc[s][r] = 0.f;

  // staging: wave-uniform LDS dest (HW adds lane*16); inverse-swizzled global src
  const int srw = l >> 3;                      // row within 8-row stage group
  const int sg  = (l & 7) ^ srw;               // inverse-swizzled k-chunk
  const size_t aoff = (size_t)(n0  + w * 32 + srw) * DIM + sg * 8;
  const size_t boff = (size_t)(q0g + w * 16 + srw) * DIM + sg * 8;

  const int rl = l & 31;
  const int kl = l >> 5;

  for (int kt = 0; kt < 8; ++kt) {
    const int k0 = kt * 64;
    #pragma unroll
    for (int j = 0; j < 4; ++j)
      gload16(A16 + aoff + (size_t)j * 8 * DIM + k0, (char*)As + (w * 4 + j) * 1024);
    #pragma unroll
    for (int j = 0; j < 2; ++j)
      gload16(B16 + boff + (size_t)j * 8 * DIM + k0, (char*)Bs + (w * 2 + j) * 1024);
    __syncthreads();

    const int br = wq * 32 + rl;               // obs row (query)
    #pragma unroll
    for (int kk = 0; kk < 4; ++kk) {
      const int cl = kk * 2 + kl;              // logical 16B k-chunk 0..7
      const half8 bf = *(const half8*)((char*)Bs + br * 128 + ((cl ^ (br & 7)) * 16));
      #pragma unroll
      for (int s = 0; s < 4; ++s) {
        const int ar = wnh * 128 + s * 32 + rl;  // bank row within block
        const half8 af = *(const half8*)((char*)As + ar * 128 + ((cl ^ (ar & 7)) * 16));
        acc[s] = __builtin_amdgcn_mfma_f32_32x32x16_f16(af, bf, acc[s], 0, 0, 0);
      }
    }
    __syncthreads();
  }

  // ---- in-register selection: per-lane smallest-8 over 64 n-scores (one query) ----
  float ts[8]; int ti[8];
  #pragma unroll
  for (int i = 0; i < 8; ++i) { ts[i] = 1e38f; ti[i] = -1; }
  const int rbase = 4 * kl;
  #pragma unroll
  for (int s = 0; s < 4; ++s) {
    #pragma unroll
    for (int r = 0; r < 16; ++r) {
      const int nl = wnh * 128 + s * 32 + (r & 3) + 8 * (r >> 2) + rbase;
      const float sc = fmaf(0.5f, b2s[nl], -acc[s][r]);
      if (sc < ts[7]) {
        float cs = sc; int ci = n0 + nl;
        #pragma unroll
        for (int p = 0; p < 8; ++p) {
          if (cs < ts[p]) {
            float tf = ts[p]; ts[p] = cs; cs = tf;
            int   tt = ti[p]; ti[p] = ci; ci = tt;
          }
        }
      }
    }
  }

  // ---- lane-pair (l ^ 32) head-merge: top-8 of 16, written to mbuf ----
  float2* mrow = mbuf + ((wq * 2 + wnh) * 32 + rl) * 8;
  for (int k = 0; k < 8; ++k) {
    const float ov = __shfl_xor(ts[0], 32);
    const int   oi = __shfl_xor(ti[0], 32);
    const bool mine = (ts[0] < ov) || (ts[0] == ov && kl == 0);
    const float wv = mine ? ts[0] : ov;
    const int   wi = mine ? ti[0] : oi;
    if (mine) {
      #pragma unroll
      for (int p = 0; p < 7; ++p) { ts[p] = ts[p+1]; ti[p] = ti[p+1]; }
      ts[7] = 1e38f; ti[7] = -1;
    }
    if (kl == 0) mrow[k] = make_float2(wv, i2f(wi));
  }
  __syncthreads();

  // ---- cross-n-half merge (sorted 8+8 -> 8) + global store ----
  if (w < 4 && l < 32) {
    const float2* pa = mbuf + ((w * 2 + 0) * 32 + l) * 8;
    const float2* pb = mbuf + ((w * 2 + 1) * 32 + l) * 8;
    float av[8], bv[8]; int ai[8], bi[8];
    #pragma unroll
    for (int j = 0; j < 8; ++j) {
      const float2 ta = pa[j]; av[j] = ta.x; ai[j] = f2i(ta.y);
      const float2 tb = pb[j]; bv[j] = tb.x; bi[j] = f2i(tb.y);
    }
    float2* outp = cand + ((size_t)(q0g + w * 32 + l) * NBLK + nblk) * 8;
    for (int k = 0; k < 8; ++k) {
      const bool ta = (av[0] <= bv[0]);
      outp[k] = make_float2(ta ? av[0] : bv[0], i2f(ta ? ai[0] : bi[0]));
      if (ta) {
        #pragma unroll
        for (int p = 0; p < 7; ++p) { av[p] = av[p+1]; ai[p] = ai[p+1]; }
        av[7] = 1e38f;
      } else {
        #pragma unroll
        for (int p = 0; p < 7; ++p) { bv[p] = bv[p+1]; bi[p] = bi[p+1]; }
        bv[7] = 1e38f;
      }
    }
  }
}

// ---------------- per-query candidate merge + exact rerank ----------------
__global__ __launch_bounds__(256) void topk_kernel(
    const float2* __restrict__ cand, const float* __restrict__ obs,
    const float* __restrict__ bank, const float* __restrict__ acts,
    float* __restrict__ out) {
  __shared__ float2 lc[NCAND];       // 25088 B
  __shared__ float2 wtop[128];
  __shared__ int   selidx[32];
  __shared__ float exd[32];
  __shared__ int   sel2[16];
  const int q    = blockIdx.x;
  const int tid  = threadIdx.x;
  const int lane = tid & 63;
  const int w    = tid >> 6;

  for (int i = tid; i < NCAND; i += 256) lc[i] = cand[(size_t)q * NCAND + i];
  __syncthreads();

  // per-wave quarter: per-lane sorted top-10, then 32 head-extractions
  float ts[10]; int ti[10];
  #pragma unroll
  for (int i = 0; i < 10; ++i) { ts[i] = 1e38f; ti[i] = -1; }
  for (int i = w * QUARTER + lane; i < (w + 1) * QUARTER; i += 64) {
    const float2 e = lc[i];
    const float s = e.x;
    if (s < ts[9]) {
      float cs = s; int ci = f2i(e.y);
      #pragma unroll
      for (int pp = 0; pp < 10; ++pp) {
        if (cs < ts[pp]) {
          float tf = ts[pp]; ts[pp] = cs; cs = tf;
          int   tt = ti[pp]; ti[pp] = ci; ci = tt;
        }
      }
    }
  }
  for (int k = 0; k < 32; ++k) {
    float bv = ts[0]; int bi = ti[0]; int bl = lane;
    #pragma unroll
    for (int o = 32; o; o >>= 1) {
      float ov = __shfl_xor(bv, o); int oi = __shfl_xor(bi, o); int ol = __shfl_xor(bl, o);
      if (ov < bv || (ov == bv && ol < bl)) { bv = ov; bi = oi; bl = ol; }
    }
    if (lane == bl) {
      #pragma unroll
      for (int pp = 0; pp < 9; ++pp) { ts[pp] = ts[pp+1]; ti[pp] = ti[pp+1]; }
      ts[9] = 1e38f; ti[9] = -1;
    }
    if (lane == 0) wtop[w * 32 + k] = make_float2(bv, i2f(bi));
  }
  __syncthreads();

  // wave 0: top-32 of the 128 wave winners
  if (w == 0) {
    float2 e0 = wtop[lane], e1 = wtop[64 + lane];
    float s0 = e0.x, s1 = e1.x;
    int   i0 = f2i(e0.y), i1 = f2i(e1.y);
    if (s1 < s0) { float tf = s0; s0 = s1; s1 = tf; int tt = i0; i0 = i1; i1 = tt; }
    for (int k = 0; k < 32; ++k) {
      float bv = s0; int bi = i0; int bl = lane;
      #pragma unroll
      for (int o = 32; o; o >>= 1) {
        float ov = __shfl_xor(bv, o); int oi = __shfl_xor(bi, o); int ol = __shfl_xor(bl, o);
        if (ov < bv || (ov == bv && ol < bl)) { bv = ov; bi = oi; bl = ol; }
      }
      if (lane == bl) { s0 = s1; i0 = i1; s1 = 1e38f; i1 = -1; }
      if (lane == 0) selidx[k] = bi;
    }
  }
  __syncthreads();

  // exact fp32 distances for the 32 candidates (one wave per candidate, round-robin)
  const float* qp = obs + (size_t)q * DIM + lane * 8;
  const float4 qa = ((const float4*)qp)[0];
  const float4 qb = ((const float4*)qp)[1];
  for (int c2 = w; c2 < 32; c2 += 4) {
    const int idx = selidx[c2];
    const float* bp_ = bank + (size_t)idx * DIM + lane * 8;
    const float4 ba = ((const float4*)bp_)[0];
    const float4 bb = ((const float4*)bp_)[1];
    const float d0 = qa.x-ba.x, d1 = qa.y-ba.y, d2 = qa.z-ba.z, d3 = qa.w-ba.w;
    const float d4 = qb.x-bb.x, d5 = qb.y-bb.y, d6 = qb.z-bb.z, d7 = qb.w-bb.w;
    float ss = d0*d0 + d1*d1 + d2*d2 + d3*d3 + d4*d4 + d5*d5 + d6*d6 + d7*d7;
    #pragma unroll
    for (int o = 32; o; o >>= 1) ss += __shfl_xor(ss, o);
    if (lane == 0) exd[c2] = ss;
  }
  __syncthreads();

  // exact top-16 of 32
  if (w == 0) {
    const float v  = (lane < 32) ? exd[lane] : 1e38f;
    const int   id = (lane < 32) ? selidx[lane] : -1;
    float lastv = -1e38f; int lastp = -1;
    for (int k = 0; k < 16; ++k) {
      float bv = 1e38f; int bi = -1; int bp = 64;
      const bool gt = (v > lastv) || (v == lastv && lane > lastp);
      if (gt) { bv = v; bi = id; bp = lane; }
      #pragma unroll
      for (int o = 32; o; o >>= 1) {
        float ov = __shfl_xor(bv, o); int oi = __shfl_xor(bi, o); int op = __shfl_xor(bp, o);
        if (ov < bv || (ov == bv && op < bp)) { bv = ov; bi = oi; bp = op; }
      }
      if (lane == 0) sel2[k] = bi;
      lastv = bv; lastp = bp;
    }
  }
  __syncthreads();

  if (tid < ADIM) {
    float s = 0.f;
    #pragma unroll
    for (int t2 = 0; t2 < KNB; ++t2) s += acts[(size_t)sel2[t2] * ADIM + tid];
    out[(size_t)q * ADIM + tid] = s * (1.0f / KNB);
  }
}

// ---------------- host launch ----------------
extern "C" void kernel_launch(void* const* d_in, const int* in_sizes, int n_in,
                              void* d_out, int out_size, void* d_ws, size_t ws_size,
                              hipStream_t stream) {
  const float* obs  = (const float*)d_in[0];
  const float* bank = (const float*)d_in[1];
  const float* acts = (const float*)d_in[2];
  float* out = (float*)d_out;
  char* ws = (char*)d_ws;

  size_t off = 0;
  auto take = [&](size_t b) { size_t o = off; off += (b + 255) & ~(size_t)255; return o; };
  const size_t off_b16  = take((size_t)NPAD * DIM * 2);          // 102.8 MB
  const size_t off_o16  = take((size_t)NQ * DIM * 2);            // 1 MB
  const size_t off_b2   = take((size_t)NPAD * 4);                // 0.4 MB
  const size_t off_cand = take((size_t)NQ * NCAND * 8);          // 25.7 MB

  _Float16* bank16 = (_Float16*)(ws + off_b16);
  _Float16* obs16  = (_Float16*)(ws + off_o16);
  float*  b2   = (float*)(ws + off_b2);
  float2* cand = (float2*)(ws + off_cand);

  convert_bank_kernel<<<NPAD / 4, 256, 0, stream>>>(bank, bank16, b2);
  convert_obs_kernel<<<NQ / 4, 256, 0, stream>>>(obs, obs16);
  gemm_select_kernel<<<dim3(NBLK, NQ / 128), 512, 0, stream>>>(bank16, obs16, b2, cand);
  topk_kernel<<<NQ, 256, 0, stream>>>(cand, obs, bank, acts, out);
}